// Round 12
// baseline (157.943 us; speedup 1.0000x reference)
//
#include <hip/hip_runtime.h>
#include <hip/hip_bf16.h>
#include <stdint.h>

typedef short bfx8 __attribute__((ext_vector_type(8)));
typedef float f32x4 __attribute__((ext_vector_type(4)));

#define MFMA16(a, b, c) __builtin_amdgcn_mfma_f32_16x16x32_bf16(a, b, c, 0, 0, 0)
// 0x77: ALU/VALU/SALU/VMEM may cross; DS_READ/DS_WRITE/MFMA pinned
#define STAGE_FENCE() __builtin_amdgcn_sched_barrier(0x77)
// 0x47: additionally pins VMEM_READ (keeps prefetch loads ABOVE this point)
#define PIN_FENCE()   __builtin_amdgcn_sched_barrier(0x47)

// LDS layout (bytes)
#define OFF_W1 0        // 64 rows x 256B
#define OFF_A1 16384    // 64 rows x 256B
#define OFF_W2 32768    // 64 rows x 128B
#define OFF_A2 40960    // 64 rows x 128B
#define OFF_CB 49152    // 324 floats
// cb byte offsets
#define CBB_B1  0
#define CBB_B2  256
#define CBB_AB1 512
#define CBB_AB2 768
#define CBB_A3  1024

__device__ __forceinline__ uint32_t pk2(float a, float b) {
    __hip_bfloat162 h = __float22bfloat162_rn(make_float2(a, b)); // low=a, high=b
    union { __hip_bfloat162 h; uint32_t u; } cv; cv.h = h; return cv.u;
}
__device__ __forceinline__ float bflo(uint32_t w) { return __uint_as_float(w << 16); }
__device__ __forceinline__ float bfhi(uint32_t w) { return __uint_as_float(w & 0xFFFF0000u); }

__device__ __forceinline__ bfx8 pack8(const float4 a, const float4 b) {
    union { bfx8 v; uint32_t u[4]; } r;
    r.u[0] = pk2(a.x, a.y); r.u[1] = pk2(a.z, a.w);
    r.u[2] = pk2(b.x, b.y); r.u[3] = pk2(b.z, b.w);
    return r.v;
}
__device__ __forceinline__ bfx8 packr(f32x4 a, f32x4 b) {
    union { bfx8 v; uint32_t u[4]; } r;
    r.u[0] = pk2(fmaxf(a[0], 0.f), fmaxf(a[1], 0.f));
    r.u[1] = pk2(fmaxf(a[2], 0.f), fmaxf(a[3], 0.f));
    r.u[2] = pk2(fmaxf(b[0], 0.f), fmaxf(b[1], 0.f));
    r.u[3] = pk2(fmaxf(b[2], 0.f), fmaxf(b[3], 0.f));
    return r.v;
}
__device__ __forceinline__ float4 ld4(const float* p) { return *(const float4*)p; }

// staging-side swizzle mixes (unchanged layout)
__device__ __forceinline__ int mix4(int row) {
    return (row & 3) | (((row >> 4) & 1) << 2) | (((row >> 3) & 1) << 3);
}
__device__ __forceinline__ int mix3(int row) {
    return (row & 3) | (((row >> 3) & 1) << 2);
}
template <int CTRL>
__device__ __forceinline__ float dppadd(float x) {
    int y = __builtin_amdgcn_update_dpp(0, __float_as_int(x), CTRL, 0xF, 0xF, false);
    return x + __int_as_float(y);
}
__device__ __forceinline__ float rowsum16(float x) {
    x = dppadd<0xB1>(x);    // quad_perm xor1
    x = dppadd<0x4E>(x);    // quad_perm xor2
    x = dppadd<0x124>(x);   // row_ror:4
    x = dppadd<0x128>(x);   // row_ror:8
    return x;
}

__global__ __launch_bounds__(512, 1) void uvagg_mfma(
    const int* __restrict__ nodes, const int* __restrict__ huv,
    const int* __restrict__ hr, const int* __restrict__ hlen,
    const float* __restrict__ v2e, const float* __restrict__ u2e,
    const float* __restrict__ r2e,
    const float* __restrict__ W1, const float* __restrict__ b1,
    const float* __restrict__ W2, const float* __restrict__ b2,
    const float* __restrict__ A1, const float* __restrict__ ab1,
    const float* __restrict__ A2, const float* __restrict__ ab2,
    const float* __restrict__ A3, const float* __restrict__ ab3f,
    float* __restrict__ out, int N, int L, int* __restrict__ cnt)
{
    __shared__ __align__(16) uint8_t smem[50448];
    float* cbf = (float*)(smem + OFF_CB);

    const int tid = threadIdx.x;
    // stage W1/A1: 4096 k-pairs each
    for (int i = tid; i < 4096; i += 512) {
        int kp = i >> 6, d = i & 63;
        int addr = d * 256 + ((((kp >> 2) ^ mix4(d)) & 15) << 4) + ((kp & 3) << 2);
        *(uint32_t*)(smem + OFF_W1 + addr) = pk2(W1[(2 * kp) * 64 + d], W1[(2 * kp + 1) * 64 + d]);
        *(uint32_t*)(smem + OFF_A1 + addr) = pk2(A1[(2 * kp) * 64 + d], A1[(2 * kp + 1) * 64 + d]);
    }
    // stage W2/A2: 2048 k-pairs each
    for (int i = tid; i < 2048; i += 512) {
        int kp = i >> 6, d = i & 63;
        int addr = d * 128 + ((((kp >> 2) ^ mix3(d)) & 7) << 4) + ((kp & 3) << 2);
        *(uint32_t*)(smem + OFF_W2 + addr) = pk2(W2[(2 * kp) * 64 + d], W2[(2 * kp + 1) * 64 + d]);
        *(uint32_t*)(smem + OFF_A2 + addr) = pk2(A2[(2 * kp) * 64 + d], A2[(2 * kp + 1) * 64 + d]);
    }
    for (int i = tid; i < 321; i += 512) {
        if (i < 64)       cbf[i]       = b1[i];
        else if (i < 128) cbf[i]       = b2[i - 64];
        else if (i < 192) cbf[i]       = ab1[i - 128];
        else if (i < 256) cbf[i]       = ab2[i - 192];
        else if (i < 320) cbf[i]       = A3[i - 256];
        else              cbf[320]     = ab3f[0];
    }
    __syncthreads();

    const int lane = tid & 63;
    const int s    = lane & 15;          // slot-in-tile (matrix column)
    const int g    = lane >> 4;          // k-group
    const int r    = s & 3;
    const int q    = s >> 2;
    const int rs   = 8 * q + r;          // pi-permuted A-row base

    // hoisted lane-constant LDS base pointers (verified identity, R11)
    const int cx = ((q >> 1) | ((q & 1) << 1));
    const int base1 = rs * 256 + ((g ^ r) << 4) + (cx << 6);
    const int base2 = rs * 128 + ((g ^ r) << 4) + ((q & 1) << 6);
    const uint8_t* pw0 = smem + (base1 ^ (0 << 6));
    const uint8_t* pw1 = smem + (base1 ^ (1 << 6));
    const uint8_t* pw2 = smem + (base1 ^ (2 << 6));
    const uint8_t* pw3 = smem + (base1 ^ (3 << 6));
    const uint8_t* pq0 = smem + (base2 ^ (0 << 6));
    const uint8_t* pq1 = smem + (base2 ^ (1 << 6));
    const uint8_t* pcb = smem + OFF_CB + 32 * g;
    const float ab3 = cbf[320];

    // ---- pipelined work queue: grab node n+1 while processing node n.
    //      The readfirstlane (= actual wait on the atomic's return) happens
    //      only AFTER the node's work, hiding the contended-line latency.
    int pending = 0;
    if (lane == 0) pending = atomicAdd(cnt, 1);
    int node = __builtin_amdgcn_readfirstlane(pending);   // first grab: exposed once

    while (node < N) {
        if (lane == 0) pending = atomicAdd(cnt, 1);       // early grab (latency hidden)

        const int hl = __builtin_amdgcn_readfirstlane(min(hlen[node], L));
        const int un = __builtin_amdgcn_readfirstlane(nodes[node]);

        // urep B-frags: A1 k-cols 64..127
        const float* ur = u2e + (size_t)un * 64;
        const bfx8 uf2 = pack8(ld4(ur + 8 * g),      ld4(ur + 8 * g + 4));
        const bfx8 uf3 = pack8(ld4(ur + 32 + 8 * g), ld4(ur + 36 + 8 * g));

        // preload ALL history indices (lane-spread)
        const int idxlane = min(lane, L - 1);
        const int iu_all = huv[(size_t)node * L + idxlane];
        const int ir_all = hr [(size_t)node * L + idxlane];

        // once per node: h1base = ab1 + A1^T[k=64..127] . urep
        f32x4 h1base[4];
        #pragma unroll
        for (int mt = 0; mt < 4; ++mt) {
            const int dof = 4 * (mt & 1) + 32 * (mt >> 1);
            h1base[mt] = *(const f32x4*)(pcb + CBB_AB1 + dof * 4);
            h1base[mt] = MFMA16(*(const bfx8*)(pw2 + OFF_A1 + dof * 256), uf2, h1base[mt]);
            h1base[mt] = MFMA16(*(const bfx8*)(pw3 + OFF_A1 + dof * 256), uf3, h1base[mt]);
        }

        float zacc = 0.0f;
        f32x4 accO[4];
        #pragma unroll
        for (int i = 0; i < 4; ++i) accO[i] = f32x4{0.f, 0.f, 0.f, 0.f};

        const int ntile = (hl + 15) >> 4;

        // pipeline prologue: tile-0 embedding loads
        float4 qa0, qa1, qa2, qa3, qb0, qb1, qb2, qb3;
        {
            const int slot0 = min(s, hl - 1);
            const int iu = __shfl(iu_all, slot0, 64);
            const int ir = __shfl(ir_all, slot0, 64);
            const float* vr = v2e + (size_t)iu * 64;
            const float* rr = r2e + (size_t)ir * 64;
            qa0 = ld4(vr + 8 * g);      qa1 = ld4(vr + 8 * g + 4);
            qa2 = ld4(vr + 32 + 8 * g); qa3 = ld4(vr + 36 + 8 * g);
            qb0 = ld4(rr + 8 * g);      qb1 = ld4(rr + 8 * g + 4);
            qb2 = ld4(rr + 32 + 8 * g); qb3 = ld4(rr + 36 + 8 * g);
        }

        for (int tt = 0; tt < ntile; ++tt) {
            const int gslot = tt * 16 + s;
            const bfx8 f0 = pack8(qa0, qa1);
            const bfx8 f1 = pack8(qa2, qa3);
            const bfx8 f2 = pack8(qb0, qb1);
            const bfx8 f3 = pack8(qb2, qb3);

            // ---- stage 1: x1 = relu(W1^T X + b1)
            f32x4 ah[4];
            #pragma unroll
            for (int mt = 0; mt < 4; ++mt) {
                const int dof = 4 * (mt & 1) + 32 * (mt >> 1);
                ah[mt] = *(const f32x4*)(pcb + CBB_B1 + dof * 4);
                ah[mt] = MFMA16(*(const bfx8*)(pw0 + OFF_W1 + dof * 256), f0, ah[mt]);
                ah[mt] = MFMA16(*(const bfx8*)(pw1 + OFF_W1 + dof * 256), f1, ah[mt]);
                ah[mt] = MFMA16(*(const bfx8*)(pw2 + OFF_W1 + dof * 256), f2, ah[mt]);
                ah[mt] = MFMA16(*(const bfx8*)(pw3 + OFF_W1 + dof * 256), f3, ah[mt]);
            }
            const bfx8 x1a = packr(ah[0], ah[1]);
            const bfx8 x1b = packr(ah[2], ah[3]);

            // ---- prefetch next tile's embeddings
            if (tt + 1 < ntile) {
                const int nslot = min(tt * 16 + 16 + s, hl - 1);
                const int niu = __shfl(iu_all, nslot, 64);
                const int nir = __shfl(ir_all, nslot, 64);
                const float* vr = v2e + (size_t)niu * 64;
                const float* rr = r2e + (size_t)nir * 64;
                qa0 = ld4(vr + 8 * g);      qa1 = ld4(vr + 8 * g + 4);
                qa2 = ld4(vr + 32 + 8 * g); qa3 = ld4(vr + 36 + 8 * g);
                qb0 = ld4(rr + 8 * g);      qb1 = ld4(rr + 8 * g + 4);
                qb2 = ld4(rr + 32 + 8 * g); qb3 = ld4(rr + 36 + 8 * g);
            }
            PIN_FENCE();

            // ---- stage 2: o = relu(W2^T x1 + b2)
            f32x4 ao[4];
            #pragma unroll
            for (int mt = 0; mt < 4; ++mt) {
                const int dof = 4 * (mt & 1) + 32 * (mt >> 1);
                ao[mt] = *(const f32x4*)(pcb + CBB_B2 + dof * 4);
                ao[mt] = MFMA16(*(const bfx8*)(pq0 + OFF_W2 + dof * 128), x1a, ao[mt]);
                ao[mt] = MFMA16(*(const bfx8*)(pq1 + OFF_W2 + dof * 128), x1b, ao[mt]);
            }
            const bfx8 oa = packr(ao[0], ao[1]);
            const bfx8 ob = packr(ao[2], ao[3]);
            STAGE_FENCE();

            // ---- stage 3 (o-half): h1 = relu(h1base + A1^T[k<64] . o)
            f32x4 h[4];
            #pragma unroll
            for (int mt = 0; mt < 4; ++mt) {
                const int dof = 4 * (mt & 1) + 32 * (mt >> 1);
                h[mt] = h1base[mt];
                h[mt] = MFMA16(*(const bfx8*)(pw0 + OFF_A1 + dof * 256), oa, h[mt]);
                h[mt] = MFMA16(*(const bfx8*)(pw1 + OFF_A1 + dof * 256), ob, h[mt]);
            }
            const bfx8 h1a = packr(h[0], h[1]);
            const bfx8 h1b = packr(h[2], h[3]);
            STAGE_FENCE();

            // ---- stage 4: h2 = relu(A2^T h1 + ab2); fused logit dot A3
            float part = 0.0f;
            #pragma unroll
            for (int mt = 0; mt < 4; ++mt) {
                const int dof = 4 * (mt & 1) + 32 * (mt >> 1);
                f32x4 h2 = *(const f32x4*)(pcb + CBB_AB2 + dof * 4);
                h2 = MFMA16(*(const bfx8*)(pq0 + OFF_A2 + dof * 128), h1a, h2);
                h2 = MFMA16(*(const bfx8*)(pq1 + OFF_A2 + dof * 128), h1b, h2);
                const f32x4 aq = *(const f32x4*)(pcb + CBB_A3 + dof * 4);
                part = fmaf(fmaxf(h2[0], 0.f), aq[0], part);
                part = fmaf(fmaxf(h2[1], 0.f), aq[1], part);
                part = fmaf(fmaxf(h2[2], 0.f), aq[2], part);
                part = fmaf(fmaxf(h2[3], 0.f), aq[3], part);
            }
            STAGE_FENCE();
            // cross-g reduce
            float p2 = part + __shfl_xor(part, 16, 64);
            const float sl = p2 + __shfl_xor(p2, 32, 64) + ab3;
            const float p = (gslot < hl) ? __expf(sl) : 0.0f;
            zacc += p;
            union { bfx8 v; uint32_t u[4]; } ua, ub;
            ua.v = oa; ub.v = ob;
            #pragma unroll
            for (int j = 0; j < 2; ++j) {
                accO[0][2*j+0] = fmaf(p, bflo(ua.u[j]),     accO[0][2*j+0]);
                accO[0][2*j+1] = fmaf(p, bfhi(ua.u[j]),     accO[0][2*j+1]);
                accO[1][2*j+0] = fmaf(p, bflo(ua.u[2 + j]), accO[1][2*j+0]);
                accO[1][2*j+1] = fmaf(p, bfhi(ua.u[2 + j]), accO[1][2*j+1]);
                accO[2][2*j+0] = fmaf(p, bflo(ub.u[j]),     accO[2][2*j+0]);
                accO[2][2*j+1] = fmaf(p, bfhi(ub.u[j]),     accO[2][2*j+1]);
                accO[3][2*j+0] = fmaf(p, bflo(ub.u[2 + j]), accO[3][2*j+0]);
                accO[3][2*j+1] = fmaf(p, bfhi(ub.u[2 + j]), accO[3][2*j+1]);
            }
        }

        // final reductions over slot-lanes: DPP only
        const float Z = rowsum16(zacc);
        #pragma unroll
        for (int mt = 0; mt < 4; ++mt)
            #pragma unroll
            for (int rr2 = 0; rr2 < 4; ++rr2)
                accO[mt][rr2] = rowsum16(accO[mt][rr2]);
        const float inv = 1.0f / Z;
        if (s == 0) {
            float* op = out + (size_t)node * 64;
            #pragma unroll
            for (int mt = 0; mt < 4; ++mt) {
                const int dof = 8 * g + 4 * (mt & 1) + 32 * (mt >> 1);
                *(float4*)(op + dof) = make_float4(accO[mt][0] * inv, accO[mt][1] * inv,
                                                   accO[mt][2] * inv, accO[mt][3] * inv);
            }
        }

        // consume the early grab only now (atomic latency was hidden by the node)
        node = __builtin_amdgcn_readfirstlane(pending);
    }
}

extern "C" void kernel_launch(void* const* d_in, const int* in_sizes, int n_in,
                              void* d_out, int out_size, void* d_ws, size_t ws_size,
                              hipStream_t stream) {
    const int*   nodes = (const int*)d_in[0];
    const int*   huv   = (const int*)d_in[1];
    const int*   hrr   = (const int*)d_in[2];
    const int*   hlen  = (const int*)d_in[3];
    const float* v2e   = (const float*)d_in[4];
    const float* u2e   = (const float*)d_in[5];
    const float* r2e   = (const float*)d_in[6];
    const float* W1    = (const float*)d_in[7];
    const float* b1    = (const float*)d_in[8];
    const float* W2    = (const float*)d_in[9];
    const float* b2    = (const float*)d_in[10];
    const float* A1    = (const float*)d_in[11];
    const float* ab1   = (const float*)d_in[12];
    const float* A2    = (const float*)d_in[13];
    const float* ab2   = (const float*)d_in[14];
    const float* A3    = (const float*)d_in[15];
    const float* ab3   = (const float*)d_in[16];
    float* out = (float*)d_out;

    const int N = in_sizes[0];
    const int L = in_sizes[1] / N;

    // work-queue counter in workspace; must be zeroed every launch
    hipMemsetAsync(d_ws, 0, sizeof(int), stream);

    int blocks = (N + 7) / 8;
    if (blocks > 512) blocks = 512;   // 2 blocks/CU co-resident capacity

    hipLaunchKernelGGL(uvagg_mfma, dim3(blocks), dim3(512), 0, stream,
                       nodes, huv, hrr, hlen, v2e, u2e, r2e,
                       W1, b1, W2, b2, A1, ab1, A2, ab2, A3, ab3,
                       out, N, L, (int*)d_ws);
}

// Round 13
// 58.484 us; speedup vs baseline: 2.7006x; 2.7006x over previous
//
#include <hip/hip_runtime.h>
#include <hip/hip_bf16.h>
#include <stdint.h>

typedef short bfx8 __attribute__((ext_vector_type(8)));
typedef float f32x4 __attribute__((ext_vector_type(4)));

#define MFMA16(a, b, c) __builtin_amdgcn_mfma_f32_16x16x32_bf16(a, b, c, 0, 0, 0)
// 0x77: ALU/VALU/SALU/VMEM may cross; DS_READ/DS_WRITE/MFMA pinned
#define STAGE_FENCE() __builtin_amdgcn_sched_barrier(0x77)

// LDS layout (bytes)
#define OFF_W1 0        // 64 rows x 256B
#define OFF_A1 16384    // 64 rows x 256B
#define OFF_W2 32768    // 64 rows x 128B
#define OFF_A2 40960    // 64 rows x 128B
#define OFF_CB 49152    // 324 floats
// cb byte offsets
#define CBB_B1  0
#define CBB_B2  256
#define CBB_AB1 512
#define CBB_AB2 768
#define CBB_A3  1024

__device__ __forceinline__ uint32_t pk2(float a, float b) {
    __hip_bfloat162 h = __float22bfloat162_rn(make_float2(a, b)); // low=a, high=b
    union { __hip_bfloat162 h; uint32_t u; } cv; cv.h = h; return cv.u;
}
__device__ __forceinline__ float bflo(uint32_t w) { return __uint_as_float(w << 16); }
__device__ __forceinline__ float bfhi(uint32_t w) { return __uint_as_float(w & 0xFFFF0000u); }

__device__ __forceinline__ bfx8 pack8(const float4 a, const float4 b) {
    union { bfx8 v; uint32_t u[4]; } r;
    r.u[0] = pk2(a.x, a.y); r.u[1] = pk2(a.z, a.w);
    r.u[2] = pk2(b.x, b.y); r.u[3] = pk2(b.z, b.w);
    return r.v;
}
__device__ __forceinline__ bfx8 packr(f32x4 a, f32x4 b) {
    union { bfx8 v; uint32_t u[4]; } r;
    r.u[0] = pk2(fmaxf(a[0], 0.f), fmaxf(a[1], 0.f));
    r.u[1] = pk2(fmaxf(a[2], 0.f), fmaxf(a[3], 0.f));
    r.u[2] = pk2(fmaxf(b[0], 0.f), fmaxf(b[1], 0.f));
    r.u[3] = pk2(fmaxf(b[2], 0.f), fmaxf(b[3], 0.f));
    return r.v;
}
__device__ __forceinline__ float4 ld4(const float* p) { return *(const float4*)p; }

// staging-side swizzle mixes (unchanged verified layout)
__device__ __forceinline__ int mix4(int row) {
    return (row & 3) | (((row >> 4) & 1) << 2) | (((row >> 3) & 1) << 3);
}
__device__ __forceinline__ int mix3(int row) {
    return (row & 3) | (((row >> 3) & 1) << 2);
}
template <int CTRL>
__device__ __forceinline__ float dppadd(float x) {
    int y = __builtin_amdgcn_update_dpp(0, __float_as_int(x), CTRL, 0xF, 0xF, false);
    return x + __int_as_float(y);
}
__device__ __forceinline__ float rowsum16(float x) {
    x = dppadd<0xB1>(x);    // quad_perm xor1
    x = dppadd<0x4E>(x);    // quad_perm xor2
    x = dppadd<0x124>(x);   // row_ror:4
    x = dppadd<0x128>(x);   // row_ror:8
    return x;
}

__global__ __launch_bounds__(256, 1) void uvagg_mfma(
    const int* __restrict__ nodes, const int* __restrict__ huv,
    const int* __restrict__ hr, const int* __restrict__ hlen,
    const float* __restrict__ v2e, const float* __restrict__ u2e,
    const float* __restrict__ r2e,
    const float* __restrict__ W1, const float* __restrict__ b1,
    const float* __restrict__ W2, const float* __restrict__ b2,
    const float* __restrict__ A1, const float* __restrict__ ab1,
    const float* __restrict__ A2, const float* __restrict__ ab2,
    const float* __restrict__ A3, const float* __restrict__ ab3f,
    float* __restrict__ out, int N, int L, int nwaves)
{
    __shared__ __align__(16) uint8_t smem[50448];
    float* cbf = (float*)(smem + OFF_CB);

    const int tid = threadIdx.x;
    // stage W1/A1: 4096 k-pairs each
    for (int i = tid; i < 4096; i += 256) {
        int kp = i >> 6, d = i & 63;
        int addr = d * 256 + ((((kp >> 2) ^ mix4(d)) & 15) << 4) + ((kp & 3) << 2);
        *(uint32_t*)(smem + OFF_W1 + addr) = pk2(W1[(2 * kp) * 64 + d], W1[(2 * kp + 1) * 64 + d]);
        *(uint32_t*)(smem + OFF_A1 + addr) = pk2(A1[(2 * kp) * 64 + d], A1[(2 * kp + 1) * 64 + d]);
    }
    // stage W2/A2: 2048 k-pairs each
    for (int i = tid; i < 2048; i += 256) {
        int kp = i >> 6, d = i & 63;
        int addr = d * 128 + ((((kp >> 2) ^ mix3(d)) & 7) << 4) + ((kp & 3) << 2);
        *(uint32_t*)(smem + OFF_W2 + addr) = pk2(W2[(2 * kp) * 64 + d], W2[(2 * kp + 1) * 64 + d]);
        *(uint32_t*)(smem + OFF_A2 + addr) = pk2(A2[(2 * kp) * 64 + d], A2[(2 * kp + 1) * 64 + d]);
    }
    for (int i = tid; i < 321; i += 256) {
        if (i < 64)       cbf[i]   = b1[i];
        else if (i < 128) cbf[i]   = b2[i - 64];
        else if (i < 192) cbf[i]   = ab1[i - 128];
        else if (i < 256) cbf[i]   = ab2[i - 192];
        else if (i < 320) cbf[i]   = A3[i - 256];
        else              cbf[320] = ab3f[0];
    }
    __syncthreads();

    const int lane = tid & 63;
    const int wid  = tid >> 6;           // 0..3
    const int s    = lane & 15;
    const int g    = lane >> 4;
    const int r    = s & 3;
    const int q    = s >> 2;
    const int rs   = 8 * q + r;

    // hoisted lane-constant LDS base pointers (bit-exact verified, R11)
    const int cx = ((q >> 1) | ((q & 1) << 1));
    const int base1 = rs * 256 + ((g ^ r) << 4) + (cx << 6);
    const int base2 = rs * 128 + ((g ^ r) << 4) + ((q & 1) << 6);
    const uint8_t* pw0 = smem + (base1 ^ (0 << 6));
    const uint8_t* pw1 = smem + (base1 ^ (1 << 6));
    const uint8_t* pw2 = smem + (base1 ^ (2 << 6));
    const uint8_t* pw3 = smem + (base1 ^ (3 << 6));
    const uint8_t* pq0 = smem + (base2 ^ (0 << 6));
    const uint8_t* pq1 = smem + (base2 ^ (1 << 6));
    const uint8_t* pcb = smem + OFF_CB + 32 * g;
    const float ab3 = cbf[320];

    #pragma unroll 1
    for (int k = 0; k < 2; ++k) {
        const int node = blockIdx.x * 4 + wid + k * nwaves;
        if (node >= N) break;

        const int hl = __builtin_amdgcn_readfirstlane(min(hlen[node], L));
        const int un = __builtin_amdgcn_readfirstlane(nodes[node]);

        const float* ur = u2e + (size_t)un * 64;
        const bfx8 uf2 = pack8(ld4(ur + 8 * g),      ld4(ur + 8 * g + 4));
        const bfx8 uf3 = pack8(ld4(ur + 32 + 8 * g), ld4(ur + 36 + 8 * g));

        const int idxlane = min(lane, L - 1);
        const int iu_all = huv[(size_t)node * L + idxlane];
        const int ir_all = hr [(size_t)node * L + idxlane];

        // once per node: h1base = ab1 + A1^T[k=64..127] . urep
        f32x4 h1base[4];
        #pragma unroll
        for (int mt = 0; mt < 4; ++mt) {
            const int dof = 4 * (mt & 1) + 32 * (mt >> 1);
            h1base[mt] = *(const f32x4*)(pcb + CBB_AB1 + dof * 4);
            h1base[mt] = MFMA16(*(const bfx8*)(pw2 + OFF_A1 + dof * 256), uf2, h1base[mt]);
            h1base[mt] = MFMA16(*(const bfx8*)(pw3 + OFF_A1 + dof * 256), uf3, h1base[mt]);
        }

        float zacc = 0.0f;
        f32x4 accO[4];
        #pragma unroll
        for (int i = 0; i < 4; ++i) accO[i] = f32x4{0.f, 0.f, 0.f, 0.f};

        const int niter = (hl + 31) >> 5;   // dual-tile: 32 slots per iteration

        for (int it = 0; it < niter; ++it) {
            const int gsA = it * 32 + s;
            const int gsB = gsA + 16;
            const int slA = min(gsA, hl - 1);
            const int slB = min(gsB, hl - 1);
            const int iuA = __shfl(iu_all, slA, 64);
            const int irA = __shfl(ir_all, slA, 64);
            const int iuB = __shfl(iu_all, slB, 64);
            const int irB = __shfl(ir_all, slB, 64);
            const float* vrA = v2e + (size_t)iuA * 64;
            const float* rrA = r2e + (size_t)irA * 64;
            const float* vrB = v2e + (size_t)iuB * 64;
            const float* rrB = r2e + (size_t)irB * 64;
            const bfx8 fA0 = pack8(ld4(vrA + 8 * g),      ld4(vrA + 8 * g + 4));
            const bfx8 fA1 = pack8(ld4(vrA + 32 + 8 * g), ld4(vrA + 36 + 8 * g));
            const bfx8 fA2 = pack8(ld4(rrA + 8 * g),      ld4(rrA + 8 * g + 4));
            const bfx8 fA3 = pack8(ld4(rrA + 32 + 8 * g), ld4(rrA + 36 + 8 * g));
            const bfx8 fB0 = pack8(ld4(vrB + 8 * g),      ld4(vrB + 8 * g + 4));
            const bfx8 fB1 = pack8(ld4(vrB + 32 + 8 * g), ld4(vrB + 36 + 8 * g));
            const bfx8 fB2 = pack8(ld4(rrB + 8 * g),      ld4(rrB + 8 * g + 4));
            const bfx8 fB3 = pack8(ld4(rrB + 32 + 8 * g), ld4(rrB + 36 + 8 * g));

            // ---- stage 1: each weight frag read once, used for A and B
            f32x4 ahA[4], ahB[4];
            #pragma unroll
            for (int mt = 0; mt < 4; ++mt) {
                const int dof = 4 * (mt & 1) + 32 * (mt >> 1);
                const f32x4 bq = *(const f32x4*)(pcb + CBB_B1 + dof * 4);
                const bfx8 w0 = *(const bfx8*)(pw0 + OFF_W1 + dof * 256);
                const bfx8 w1 = *(const bfx8*)(pw1 + OFF_W1 + dof * 256);
                const bfx8 w2 = *(const bfx8*)(pw2 + OFF_W1 + dof * 256);
                const bfx8 w3 = *(const bfx8*)(pw3 + OFF_W1 + dof * 256);
                ahA[mt] = bq; ahB[mt] = bq;
                ahA[mt] = MFMA16(w0, fA0, ahA[mt]);
                ahB[mt] = MFMA16(w0, fB0, ahB[mt]);
                ahA[mt] = MFMA16(w1, fA1, ahA[mt]);
                ahB[mt] = MFMA16(w1, fB1, ahB[mt]);
                ahA[mt] = MFMA16(w2, fA2, ahA[mt]);
                ahB[mt] = MFMA16(w2, fB2, ahB[mt]);
                ahA[mt] = MFMA16(w3, fA3, ahA[mt]);
                ahB[mt] = MFMA16(w3, fB3, ahB[mt]);
            }
            const bfx8 x1aA = packr(ahA[0], ahA[1]);
            const bfx8 x1bA = packr(ahA[2], ahA[3]);
            const bfx8 x1aB = packr(ahB[0], ahB[1]);
            const bfx8 x1bB = packr(ahB[2], ahB[3]);
            STAGE_FENCE();

            // ---- stage 2
            f32x4 aoA[4], aoB[4];
            #pragma unroll
            for (int mt = 0; mt < 4; ++mt) {
                const int dof = 4 * (mt & 1) + 32 * (mt >> 1);
                const f32x4 bq = *(const f32x4*)(pcb + CBB_B2 + dof * 4);
                const bfx8 w0 = *(const bfx8*)(pq0 + OFF_W2 + dof * 128);
                const bfx8 w1 = *(const bfx8*)(pq1 + OFF_W2 + dof * 128);
                aoA[mt] = bq; aoB[mt] = bq;
                aoA[mt] = MFMA16(w0, x1aA, aoA[mt]);
                aoB[mt] = MFMA16(w0, x1aB, aoB[mt]);
                aoA[mt] = MFMA16(w1, x1bA, aoA[mt]);
                aoB[mt] = MFMA16(w1, x1bB, aoB[mt]);
            }
            const bfx8 oaA = packr(aoA[0], aoA[1]);
            const bfx8 obA = packr(aoA[2], aoA[3]);
            const bfx8 oaB = packr(aoB[0], aoB[1]);
            const bfx8 obB = packr(aoB[2], aoB[3]);
            STAGE_FENCE();

            // ---- stage 3 (o-half): h1 = relu(h1base + A1^T[k<64] . o)
            f32x4 hA[4], hB[4];
            #pragma unroll
            for (int mt = 0; mt < 4; ++mt) {
                const int dof = 4 * (mt & 1) + 32 * (mt >> 1);
                const bfx8 w0 = *(const bfx8*)(pw0 + OFF_A1 + dof * 256);
                const bfx8 w1 = *(const bfx8*)(pw1 + OFF_A1 + dof * 256);
                hA[mt] = h1base[mt]; hB[mt] = h1base[mt];
                hA[mt] = MFMA16(w0, oaA, hA[mt]);
                hB[mt] = MFMA16(w0, oaB, hB[mt]);
                hA[mt] = MFMA16(w1, obA, hA[mt]);
                hB[mt] = MFMA16(w1, obB, hB[mt]);
            }
            const bfx8 h1aA = packr(hA[0], hA[1]);
            const bfx8 h1bA = packr(hA[2], hA[3]);
            const bfx8 h1aB = packr(hB[0], hB[1]);
            const bfx8 h1bB = packr(hB[2], hB[3]);
            STAGE_FENCE();

            // ---- stage 4 + fused logit dot
            float partA = 0.0f, partB = 0.0f;
            #pragma unroll
            for (int mt = 0; mt < 4; ++mt) {
                const int dof = 4 * (mt & 1) + 32 * (mt >> 1);
                const f32x4 bq = *(const f32x4*)(pcb + CBB_AB2 + dof * 4);
                const bfx8 w0 = *(const bfx8*)(pq0 + OFF_A2 + dof * 128);
                const bfx8 w1 = *(const bfx8*)(pq1 + OFF_A2 + dof * 128);
                f32x4 h2A = bq, h2B = bq;
                h2A = MFMA16(w0, h1aA, h2A);
                h2B = MFMA16(w0, h1aB, h2B);
                h2A = MFMA16(w1, h1bA, h2A);
                h2B = MFMA16(w1, h1bB, h2B);
                const f32x4 aq = *(const f32x4*)(pcb + CBB_A3 + dof * 4);
                partA = fmaf(fmaxf(h2A[0], 0.f), aq[0], partA);
                partA = fmaf(fmaxf(h2A[1], 0.f), aq[1], partA);
                partA = fmaf(fmaxf(h2A[2], 0.f), aq[2], partA);
                partA = fmaf(fmaxf(h2A[3], 0.f), aq[3], partA);
                partB = fmaf(fmaxf(h2B[0], 0.f), aq[0], partB);
                partB = fmaf(fmaxf(h2B[1], 0.f), aq[1], partB);
                partB = fmaf(fmaxf(h2B[2], 0.f), aq[2], partB);
                partB = fmaf(fmaxf(h2B[3], 0.f), aq[3], partB);
            }
            STAGE_FENCE();
            // cross-g reduce + no-max softmax weights
            float p2A = partA + __shfl_xor(partA, 16, 64);
            const float slvA = p2A + __shfl_xor(p2A, 32, 64) + ab3;
            float p2B = partB + __shfl_xor(partB, 16, 64);
            const float slvB = p2B + __shfl_xor(p2B, 32, 64) + ab3;
            const float pA = (gsA < hl) ? __expf(slvA) : 0.0f;
            const float pB = (gsB < hl) ? __expf(slvB) : 0.0f;
            zacc += pA + pB;
            union { bfx8 v; uint32_t u[4]; } uaA, ubA, uaB, ubB;
            uaA.v = oaA; ubA.v = obA; uaB.v = oaB; ubB.v = obB;
            #pragma unroll
            for (int j = 0; j < 2; ++j) {
                accO[0][2*j+0] = fmaf(pA, bflo(uaA.u[j]),     accO[0][2*j+0]);
                accO[0][2*j+1] = fmaf(pA, bfhi(uaA.u[j]),     accO[0][2*j+1]);
                accO[1][2*j+0] = fmaf(pA, bflo(uaA.u[2 + j]), accO[1][2*j+0]);
                accO[1][2*j+1] = fmaf(pA, bfhi(uaA.u[2 + j]), accO[1][2*j+1]);
                accO[2][2*j+0] = fmaf(pA, bflo(ubA.u[j]),     accO[2][2*j+0]);
                accO[2][2*j+1] = fmaf(pA, bfhi(ubA.u[j]),     accO[2][2*j+1]);
                accO[3][2*j+0] = fmaf(pA, bflo(ubA.u[2 + j]), accO[3][2*j+0]);
                accO[3][2*j+1] = fmaf(pA, bfhi(ubA.u[2 + j]), accO[3][2*j+1]);
                accO[0][2*j+0] = fmaf(pB, bflo(uaB.u[j]),     accO[0][2*j+0]);
                accO[0][2*j+1] = fmaf(pB, bfhi(uaB.u[j]),     accO[0][2*j+1]);
                accO[1][2*j+0] = fmaf(pB, bflo(uaB.u[2 + j]), accO[1][2*j+0]);
                accO[1][2*j+1] = fmaf(pB, bfhi(uaB.u[2 + j]), accO[1][2*j+1]);
                accO[2][2*j+0] = fmaf(pB, bflo(ubB.u[j]),     accO[2][2*j+0]);
                accO[2][2*j+1] = fmaf(pB, bfhi(ubB.u[j]),     accO[2][2*j+1]);
                accO[3][2*j+0] = fmaf(pB, bflo(ubB.u[2 + j]), accO[3][2*j+0]);
                accO[3][2*j+1] = fmaf(pB, bfhi(ubB.u[2 + j]), accO[3][2*j+1]);
            }
        }

        // final reductions over slot-lanes: DPP only
        const float Z = rowsum16(zacc);
        #pragma unroll
        for (int mt = 0; mt < 4; ++mt)
            #pragma unroll
            for (int rr2 = 0; rr2 < 4; ++rr2)
                accO[mt][rr2] = rowsum16(accO[mt][rr2]);
        const float inv = 1.0f / Z;
        if (s == 0) {
            float* op = out + (size_t)node * 64;
            #pragma unroll
            for (int mt = 0; mt < 4; ++mt) {
                const int dof = 8 * g + 4 * (mt & 1) + 32 * (mt >> 1);
                *(float4*)(op + dof) = make_float4(accO[mt][0] * inv, accO[mt][1] * inv,
                                                   accO[mt][2] * inv, accO[mt][3] * inv);
            }
        }
    }
}

extern "C" void kernel_launch(void* const* d_in, const int* in_sizes, int n_in,
                              void* d_out, int out_size, void* d_ws, size_t ws_size,
                              hipStream_t stream) {
    const int*   nodes = (const int*)d_in[0];
    const int*   huv   = (const int*)d_in[1];
    const int*   hrr   = (const int*)d_in[2];
    const int*   hlen  = (const int*)d_in[3];
    const float* v2e   = (const float*)d_in[4];
    const float* u2e   = (const float*)d_in[5];
    const float* r2e   = (const float*)d_in[6];
    const float* W1    = (const float*)d_in[7];
    const float* b1    = (const float*)d_in[8];
    const float* W2    = (const float*)d_in[9];
    const float* b2    = (const float*)d_in[10];
    const float* A1    = (const float*)d_in[11];
    const float* ab1   = (const float*)d_in[12];
    const float* A2    = (const float*)d_in[13];
    const float* ab2   = (const float*)d_in[14];
    const float* A3    = (const float*)d_in[15];
    const float* ab3   = (const float*)d_in[16];
    float* out = (float*)d_out;

    const int N = in_sizes[0];
    const int L = in_sizes[1] / N;

    // 256-thr blocks, 4 waves each, 2 nodes per wave (stride nwaves)
    const int blocks = (N + 7) / 8;
    const int nwaves = blocks * 4;

    hipLaunchKernelGGL(uvagg_mfma, dim3(blocks), dim3(256), 0, stream,
                       nodes, huv, hrr, hlen, v2e, u2e, r2e,
                       W1, b1, W2, b2, A1, ab1, A2, ab2, A3, ab3,
                       out, N, L, nwaves);
}

// Round 14
// 40.335 us; speedup vs baseline: 3.9158x; 1.4500x over previous
//
#include <hip/hip_runtime.h>
#include <hip/hip_bf16.h>
#include <stdint.h>

typedef short bfx8 __attribute__((ext_vector_type(8)));
typedef float f32x4 __attribute__((ext_vector_type(4)));

#define MFMA16(a, b, c) __builtin_amdgcn_mfma_f32_16x16x32_bf16(a, b, c, 0, 0, 0)
// 0x77: ALU/VALU/SALU/VMEM may cross; DS_READ/DS_WRITE/MFMA pinned
#define STAGE_FENCE() __builtin_amdgcn_sched_barrier(0x77)
// 0x47: additionally pins VMEM_READ (keeps prefetch loads ABOVE this point)
#define PIN_FENCE()   __builtin_amdgcn_sched_barrier(0x47)

// LDS layout (bytes)
#define OFF_W1 0        // 64 rows x 256B  (W1 k=0..63 only used in steady state)
#define OFF_A1 16384    // 64 rows x 256B
#define OFF_W2 32768    // 64 rows x 128B
#define OFF_A2 40960    // 64 rows x 128B
#define OFF_CB 49152    // 324 floats
#define OFF_TB 50448    // 5 rows x 272B: TB[r][d] = b1[d] + sum_k W1[64+k][d]*r2e[r][k]
// cb byte offsets
#define CBB_B1  0
#define CBB_B2  256
#define CBB_AB1 512
#define CBB_AB2 768
#define CBB_A3  1024

__device__ __forceinline__ uint32_t pk2(float a, float b) {
    __hip_bfloat162 h = __float22bfloat162_rn(make_float2(a, b)); // low=a, high=b
    union { __hip_bfloat162 h; uint32_t u; } cv; cv.h = h; return cv.u;
}
__device__ __forceinline__ float bflo(uint32_t w) { return __uint_as_float(w << 16); }
__device__ __forceinline__ float bfhi(uint32_t w) { return __uint_as_float(w & 0xFFFF0000u); }

__device__ __forceinline__ bfx8 pack8(const float4 a, const float4 b) {
    union { bfx8 v; uint32_t u[4]; } r;
    r.u[0] = pk2(a.x, a.y); r.u[1] = pk2(a.z, a.w);
    r.u[2] = pk2(b.x, b.y); r.u[3] = pk2(b.z, b.w);
    return r.v;
}
__device__ __forceinline__ bfx8 packr(f32x4 a, f32x4 b) {
    union { bfx8 v; uint32_t u[4]; } r;
    r.u[0] = pk2(fmaxf(a[0], 0.f), fmaxf(a[1], 0.f));
    r.u[1] = pk2(fmaxf(a[2], 0.f), fmaxf(a[3], 0.f));
    r.u[2] = pk2(fmaxf(b[0], 0.f), fmaxf(b[1], 0.f));
    r.u[3] = pk2(fmaxf(b[2], 0.f), fmaxf(b[3], 0.f));
    return r.v;
}
__device__ __forceinline__ float4 ld4(const float* p) { return *(const float4*)p; }

// staging-side swizzle mixes (unchanged verified layout)
__device__ __forceinline__ int mix4(int row) {
    return (row & 3) | (((row >> 4) & 1) << 2) | (((row >> 3) & 1) << 3);
}
__device__ __forceinline__ int mix3(int row) {
    return (row & 3) | (((row >> 3) & 1) << 2);
}
template <int CTRL>
__device__ __forceinline__ float dppadd(float x) {
    int y = __builtin_amdgcn_update_dpp(0, __float_as_int(x), CTRL, 0xF, 0xF, false);
    return x + __int_as_float(y);
}
__device__ __forceinline__ float rowsum16(float x) {
    x = dppadd<0xB1>(x);    // quad_perm xor1
    x = dppadd<0x4E>(x);    // quad_perm xor2
    x = dppadd<0x124>(x);   // row_ror:4
    x = dppadd<0x128>(x);   // row_ror:8
    return x;
}

__global__ __launch_bounds__(512, 1) void uvagg_mfma(
    const int* __restrict__ nodes, const int* __restrict__ huv,
    const int* __restrict__ hr, const int* __restrict__ hlen,
    const float* __restrict__ v2e, const float* __restrict__ u2e,
    const float* __restrict__ r2e,
    const float* __restrict__ W1, const float* __restrict__ b1,
    const float* __restrict__ W2, const float* __restrict__ b2,
    const float* __restrict__ A1, const float* __restrict__ ab1,
    const float* __restrict__ A2, const float* __restrict__ ab2,
    const float* __restrict__ A3, const float* __restrict__ ab3f,
    float* __restrict__ out, int N, int L, int nwaves)
{
    __shared__ __align__(16) uint8_t smem[51808];
    float* cbf = (float*)(smem + OFF_CB);

    const int tid = threadIdx.x;
    // stage W1/A1: 4096 k-pairs each (W1 k>=64 rows staged but unused in loop; harmless)
    for (int i = tid; i < 4096; i += 512) {
        int kp = i >> 6, d = i & 63;
        int addr = d * 256 + ((((kp >> 2) ^ mix4(d)) & 15) << 4) + ((kp & 3) << 2);
        *(uint32_t*)(smem + OFF_W1 + addr) = pk2(W1[(2 * kp) * 64 + d], W1[(2 * kp + 1) * 64 + d]);
        *(uint32_t*)(smem + OFF_A1 + addr) = pk2(A1[(2 * kp) * 64 + d], A1[(2 * kp + 1) * 64 + d]);
    }
    // stage W2/A2: 2048 k-pairs each
    for (int i = tid; i < 2048; i += 512) {
        int kp = i >> 6, d = i & 63;
        int addr = d * 128 + ((((kp >> 2) ^ mix3(d)) & 7) << 4) + ((kp & 3) << 2);
        *(uint32_t*)(smem + OFF_W2 + addr) = pk2(W2[(2 * kp) * 64 + d], W2[(2 * kp + 1) * 64 + d]);
        *(uint32_t*)(smem + OFF_A2 + addr) = pk2(A2[(2 * kp) * 64 + d], A2[(2 * kp + 1) * 64 + d]);
    }
    for (int i = tid; i < 321; i += 512) {
        if (i < 64)       cbf[i]   = b1[i];
        else if (i < 128) cbf[i]   = b2[i - 64];
        else if (i < 192) cbf[i]   = ab1[i - 128];
        else if (i < 256) cbf[i]   = ab2[i - 192];
        else if (i < 320) cbf[i]   = A3[i - 256];
        else              cbf[320] = ab3f[0];
    }
    // rating table: TB[r][d] = b1[d] + sum_k W1[64+k][d] * r2e[r][k]   (fp32, 272B row stride)
    for (int i = tid; i < 320; i += 512) {
        const int rr_ = i >> 6, d = i & 63;
        const float* wcol = W1 + 64 * 64 + d;     // W1 rows 64..127, column d
        const float* rrow = r2e + rr_ * 64;
        float a0 = b1[d], a1 = 0.f, a2 = 0.f, a3 = 0.f;
        #pragma unroll
        for (int k2 = 0; k2 < 64; k2 += 4) {
            a0 = fmaf(wcol[(k2 + 0) * 64], rrow[k2 + 0], a0);
            a1 = fmaf(wcol[(k2 + 1) * 64], rrow[k2 + 1], a1);
            a2 = fmaf(wcol[(k2 + 2) * 64], rrow[k2 + 2], a2);
            a3 = fmaf(wcol[(k2 + 3) * 64], rrow[k2 + 3], a3);
        }
        *(float*)(smem + OFF_TB + rr_ * 272 + d * 4) = (a0 + a1) + (a2 + a3);
    }
    __syncthreads();

    const int lane = tid & 63;
    const int wid  = tid >> 6;
    const int s    = lane & 15;          // slot-in-tile (matrix column)
    const int g    = lane >> 4;          // k-group
    const int r    = s & 3;
    const int q    = s >> 2;
    const int rs   = 8 * q + r;          // pi-permuted A-row base

    // hoisted lane-constant LDS base pointers (bit-exact verified, R11)
    const int cx = ((q >> 1) | ((q & 1) << 1));
    const int base1 = rs * 256 + ((g ^ r) << 4) + (cx << 6);
    const int base2 = rs * 128 + ((g ^ r) << 4) + ((q & 1) << 6);
    const uint8_t* pw0 = smem + (base1 ^ (0 << 6));
    const uint8_t* pw1 = smem + (base1 ^ (1 << 6));
    const uint8_t* pw2 = smem + (base1 ^ (2 << 6));
    const uint8_t* pw3 = smem + (base1 ^ (3 << 6));
    const uint8_t* pq0 = smem + (base2 ^ (0 << 6));
    const uint8_t* pq1 = smem + (base2 ^ (1 << 6));
    const uint8_t* pcb = smem + OFF_CB + 32 * g;
    const uint8_t* ptb = smem + OFF_TB + 32 * g;   // + rating*272 + dof*4
    const float ab3 = cbf[320];

    for (int node = blockIdx.x * 8 + wid; node < N; node += nwaves) {
        const int hl = __builtin_amdgcn_readfirstlane(min(hlen[node], L));
        const int un = __builtin_amdgcn_readfirstlane(nodes[node]);

        const float* ur = u2e + (size_t)un * 64;
        const bfx8 uf2 = pack8(ld4(ur + 8 * g),      ld4(ur + 8 * g + 4));
        const bfx8 uf3 = pack8(ld4(ur + 32 + 8 * g), ld4(ur + 36 + 8 * g));

        const int idxlane = min(lane, L - 1);
        const int iu_all = huv[(size_t)node * L + idxlane];
        const int ir_all = hr [(size_t)node * L + idxlane];

        // once per node: h1base = ab1 + A1^T[k=64..127] . urep
        f32x4 h1base[4];
        #pragma unroll
        for (int mt = 0; mt < 4; ++mt) {
            const int dof = 4 * (mt & 1) + 32 * (mt >> 1);
            h1base[mt] = *(const f32x4*)(pcb + CBB_AB1 + dof * 4);
            h1base[mt] = MFMA16(*(const bfx8*)(pw2 + OFF_A1 + dof * 256), uf2, h1base[mt]);
            h1base[mt] = MFMA16(*(const bfx8*)(pw3 + OFF_A1 + dof * 256), uf3, h1base[mt]);
        }

        float zacc = 0.0f;
        f32x4 accO[4];
        #pragma unroll
        for (int i = 0; i < 4; ++i) accO[i] = f32x4{0.f, 0.f, 0.f, 0.f};

        const int ntile = (hl + 15) >> 4;

        // pipeline prologue: tile-0 item-embedding load + rating index
        float4 qa0, qa1, qa2, qa3;
        int irs;
        {
            const int slot0 = min(s, hl - 1);
            const int iu = __shfl(iu_all, slot0, 64);
            irs = __shfl(ir_all, slot0, 64);
            const float* vr = v2e + (size_t)iu * 64;
            qa0 = ld4(vr + 8 * g);      qa1 = ld4(vr + 8 * g + 4);
            qa2 = ld4(vr + 32 + 8 * g); qa3 = ld4(vr + 36 + 8 * g);
        }

        for (int tt = 0; tt < ntile; ++tt) {
            const int gslot = tt * 16 + s;
            const bfx8 f0 = pack8(qa0, qa1);
            const bfx8 f1 = pack8(qa2, qa3);
            const uint8_t* ptbr = ptb + irs * 272;

            // ---- stage 1: x1 = relu(TB[rating] + W1u^T e_uv)
            f32x4 ah[4];
            #pragma unroll
            for (int mt = 0; mt < 4; ++mt) {
                const int dof = 4 * (mt & 1) + 32 * (mt >> 1);
                ah[mt] = *(const f32x4*)(ptbr + dof * 4);
                ah[mt] = MFMA16(*(const bfx8*)(pw0 + OFF_W1 + dof * 256), f0, ah[mt]);
                ah[mt] = MFMA16(*(const bfx8*)(pw1 + OFF_W1 + dof * 256), f1, ah[mt]);
            }
            const bfx8 x1a = packr(ah[0], ah[1]);
            const bfx8 x1b = packr(ah[2], ah[3]);

            // ---- prefetch next tile's item embedding + rating
            if (tt + 1 < ntile) {
                const int nslot = min(tt * 16 + 16 + s, hl - 1);
                const int niu = __shfl(iu_all, nslot, 64);
                irs = __shfl(ir_all, nslot, 64);
                const float* vr = v2e + (size_t)niu * 64;
                qa0 = ld4(vr + 8 * g);      qa1 = ld4(vr + 8 * g + 4);
                qa2 = ld4(vr + 32 + 8 * g); qa3 = ld4(vr + 36 + 8 * g);
            }
            PIN_FENCE();

            // ---- stage 2: o = relu(W2^T x1 + b2)
            f32x4 ao[4];
            #pragma unroll
            for (int mt = 0; mt < 4; ++mt) {
                const int dof = 4 * (mt & 1) + 32 * (mt >> 1);
                ao[mt] = *(const f32x4*)(pcb + CBB_B2 + dof * 4);
                ao[mt] = MFMA16(*(const bfx8*)(pq0 + OFF_W2 + dof * 128), x1a, ao[mt]);
                ao[mt] = MFMA16(*(const bfx8*)(pq1 + OFF_W2 + dof * 128), x1b, ao[mt]);
            }
            const bfx8 oa = packr(ao[0], ao[1]);
            const bfx8 ob = packr(ao[2], ao[3]);
            STAGE_FENCE();

            // ---- stage 3 (o-half): h1 = relu(h1base + A1^T[k<64] . o)
            f32x4 h[4];
            #pragma unroll
            for (int mt = 0; mt < 4; ++mt) {
                const int dof = 4 * (mt & 1) + 32 * (mt >> 1);
                h[mt] = h1base[mt];
                h[mt] = MFMA16(*(const bfx8*)(pw0 + OFF_A1 + dof * 256), oa, h[mt]);
                h[mt] = MFMA16(*(const bfx8*)(pw1 + OFF_A1 + dof * 256), ob, h[mt]);
            }
            const bfx8 h1a = packr(h[0], h[1]);
            const bfx8 h1b = packr(h[2], h[3]);
            STAGE_FENCE();

            // ---- stage 4: h2 = relu(A2^T h1 + ab2); fused logit dot A3
            float part = 0.0f;
            #pragma unroll
            for (int mt = 0; mt < 4; ++mt) {
                const int dof = 4 * (mt & 1) + 32 * (mt >> 1);
                f32x4 h2 = *(const f32x4*)(pcb + CBB_AB2 + dof * 4);
                h2 = MFMA16(*(const bfx8*)(pq0 + OFF_A2 + dof * 128), h1a, h2);
                h2 = MFMA16(*(const bfx8*)(pq1 + OFF_A2 + dof * 128), h1b, h2);
                const f32x4 aq = *(const f32x4*)(pcb + CBB_A3 + dof * 4);
                part = fmaf(fmaxf(h2[0], 0.f), aq[0], part);
                part = fmaf(fmaxf(h2[1], 0.f), aq[1], part);
                part = fmaf(fmaxf(h2[2], 0.f), aq[2], part);
                part = fmaf(fmaxf(h2[3], 0.f), aq[3], part);
            }
            STAGE_FENCE();
            // cross-g reduce
            float p2 = part + __shfl_xor(part, 16, 64);
            const float sl = p2 + __shfl_xor(p2, 32, 64) + ab3;
            const float p = (gslot < hl) ? __expf(sl) : 0.0f;
            zacc += p;
            union { bfx8 v; uint32_t u[4]; } ua, ub;
            ua.v = oa; ub.v = ob;
            #pragma unroll
            for (int j = 0; j < 2; ++j) {
                accO[0][2*j+0] = fmaf(p, bflo(ua.u[j]),     accO[0][2*j+0]);
                accO[0][2*j+1] = fmaf(p, bfhi(ua.u[j]),     accO[0][2*j+1]);
                accO[1][2*j+0] = fmaf(p, bflo(ua.u[2 + j]), accO[1][2*j+0]);
                accO[1][2*j+1] = fmaf(p, bfhi(ua.u[2 + j]), accO[1][2*j+1]);
                accO[2][2*j+0] = fmaf(p, bflo(ub.u[j]),     accO[2][2*j+0]);
                accO[2][2*j+1] = fmaf(p, bfhi(ub.u[j]),     accO[2][2*j+1]);
                accO[3][2*j+0] = fmaf(p, bflo(ub.u[2 + j]), accO[3][2*j+0]);
                accO[3][2*j+1] = fmaf(p, bfhi(ub.u[2 + j]), accO[3][2*j+1]);
            }
        }

        // final reductions over slot-lanes: DPP only
        const float Z = rowsum16(zacc);
        #pragma unroll
        for (int mt = 0; mt < 4; ++mt)
            #pragma unroll
            for (int rr2 = 0; rr2 < 4; ++rr2)
                accO[mt][rr2] = rowsum16(accO[mt][rr2]);
        const float inv = 1.0f / Z;
        if (s == 0) {
            float* op = out + (size_t)node * 64;
            #pragma unroll
            for (int mt = 0; mt < 4; ++mt) {
                const int dof = 8 * g + 4 * (mt & 1) + 32 * (mt >> 1);
                *(float4*)(op + dof) = make_float4(accO[mt][0] * inv, accO[mt][1] * inv,
                                                   accO[mt][2] * inv, accO[mt][3] * inv);
            }
        }
    }
}

extern "C" void kernel_launch(void* const* d_in, const int* in_sizes, int n_in,
                              void* d_out, int out_size, void* d_ws, size_t ws_size,
                              hipStream_t stream) {
    const int*   nodes = (const int*)d_in[0];
    const int*   huv   = (const int*)d_in[1];
    const int*   hrr   = (const int*)d_in[2];
    const int*   hlen  = (const int*)d_in[3];
    const float* v2e   = (const float*)d_in[4];
    const float* u2e   = (const float*)d_in[5];
    const float* r2e   = (const float*)d_in[6];
    const float* W1    = (const float*)d_in[7];
    const float* b1    = (const float*)d_in[8];
    const float* W2    = (const float*)d_in[9];
    const float* b2    = (const float*)d_in[10];
    const float* A1    = (const float*)d_in[11];
    const float* ab1   = (const float*)d_in[12];
    const float* A2    = (const float*)d_in[13];
    const float* ab2   = (const float*)d_in[14];
    const float* A3    = (const float*)d_in[15];
    const float* ab3   = (const float*)d_in[16];
    float* out = (float*)d_out;

    const int N = in_sizes[0];
    const int L = in_sizes[1] / N;

    // persistent grid: co-resident capacity (2 blocks/CU x 256 CU)
    int blocks = (N + 7) / 8;
    if (blocks > 512) blocks = 512;
    const int nwaves = blocks * 8;

    hipLaunchKernelGGL(uvagg_mfma, dim3(blocks), dim3(512), 0, stream,
                       nodes, huv, hrr, hlen, v2e, u2e, r2e,
                       W1, b1, W2, b2, A1, ab1, A2, ab2, A3, ab3,
                       out, N, L, nwaves);
}